// Round 1
// baseline (390.029 us; speedup 1.0000x reference)
//
#include <hip/hip_runtime.h>

#define EPS_BN 1e-5f
#define HW4 65536u            // float4 elements per channel plane (512*512/4)
#define MSG_OFF4 5242880u     // float4 offset of `message` inside d_out (8*10*HW4)

typedef unsigned int u32;
typedef __fp16 h2 __attribute__((ext_vector_type(2)));

union W32 { u32 u; float f; h2 h; };

__device__ __forceinline__ float asf(u32 u){ W32 w; w.u = u; return w.f; }
__device__ __forceinline__ h2    ash(u32 u){ W32 w; w.u = u; return w.h; }
__device__ __forceinline__ u32 packh(float a, float b){
  W32 w; w.h.x = (__fp16)a; w.h.y = (__fp16)b; return w.u;
}

#if __has_builtin(__builtin_amdgcn_fdot2)
__device__ __forceinline__ float dot2(h2 a, h2 b, float c){
  return __builtin_amdgcn_fdot2(a, b, c, false);
}
#else
__device__ __forceinline__ float dot2(h2 a, h2 b, float c){
  return c + (float)a.x * (float)b.x + (float)a.y * (float)b.y;
}
#endif

#if __has_builtin(__builtin_amdgcn_cvt_pkrtz)
__device__ __forceinline__ h2 pk(float a, float b){ return __builtin_amdgcn_cvt_pkrtz(a, b); }
#else
__device__ __forceinline__ h2 pk(float a, float b){ h2 r; r.x = (__fp16)a; r.y = (__fp16)b; return r; }
#endif

// ws (u32 words) layout, BN-folded, f16 K-pair packed weights:
//    0: W1p [10][32] u32   pair cp = channels (2cp,2cp+1) of concat(xh1,xh2)
//  320: B1  [32]  f32
//  352: W2p [16][16] u32   K=32 -> 16 pairs; outputs padded 10->16
//  608: B2  [16]  f32
//  624: W3p [10][32] u32   concat(xf,message)
//  944: B3  [32]  f32
//  976: W4p [16][16] u32
// 1232: B4  [16]  f32
// total 1248 words = 4992 B

extern "C" __global__ void prep_kernel(
  const float* __restrict__ w1, const float* __restrict__ g1, const float* __restrict__ b1, const float* __restrict__ m1, const float* __restrict__ v1,
  const float* __restrict__ w2, const float* __restrict__ g2, const float* __restrict__ b2, const float* __restrict__ m2, const float* __restrict__ v2,
  const float* __restrict__ w3, const float* __restrict__ g3, const float* __restrict__ b3, const float* __restrict__ m3, const float* __restrict__ v3,
  const float* __restrict__ w4, const float* __restrict__ g4, const float* __restrict__ b4, const float* __restrict__ m4, const float* __restrict__ v4,
  u32* __restrict__ ws)
{
  const int t = threadIdx.x;
  // W1p [10][32]: w1 is [32][20]
  for (int i = t; i < 320; i += 256){ int cp = i >> 5, o = i & 31;
    float sc = g1[o] * rsqrtf(v1[o] + EPS_BN);
    ws[i] = packh(w1[o*20 + 2*cp] * sc, w1[o*20 + 2*cp + 1] * sc); }
  for (int i = t; i < 32; i += 256){
    float sc = g1[i] * rsqrtf(v1[i] + EPS_BN);
    W32 w; w.f = b1[i] - m1[i] * sc; ws[320 + i] = w.u; }
  // W2p [16][16]: w2 is [10][32]
  for (int i = t; i < 256; i += 256){ int cp = i >> 4, o = i & 15; u32 val = 0u;
    if (o < 10){ float sc = g2[o] * rsqrtf(v2[o] + EPS_BN);
      val = packh(w2[o*32 + 2*cp] * sc, w2[o*32 + 2*cp + 1] * sc); }
    ws[352 + i] = val; }
  for (int i = t; i < 16; i += 256){ W32 w; w.f = 0.f;
    if (i < 10){ float sc = g2[i] * rsqrtf(v2[i] + EPS_BN); w.f = b2[i] - m2[i] * sc; }
    ws[608 + i] = w.u; }
  // W3p [10][32]: w3 is [32][20]
  for (int i = t; i < 320; i += 256){ int cp = i >> 5, o = i & 31;
    float sc = g3[o] * rsqrtf(v3[o] + EPS_BN);
    ws[624 + i] = packh(w3[o*20 + 2*cp] * sc, w3[o*20 + 2*cp + 1] * sc); }
  for (int i = t; i < 32; i += 256){
    float sc = g3[i] * rsqrtf(v3[i] + EPS_BN);
    W32 w; w.f = b3[i] - m3[i] * sc; ws[944 + i] = w.u; }
  // W4p [16][16]: w4 is [10][32]
  for (int i = t; i < 256; i += 256){ int cp = i >> 4, o = i & 15; u32 val = 0u;
    if (o < 10){ float sc = g4[o] * rsqrtf(v4[o] + EPS_BN);
      val = packh(w4[o*32 + 2*cp] * sc, w4[o*32 + 2*cp + 1] * sc); }
    ws[976 + i] = val; }
  for (int i = t; i < 16; i += 256){ W32 w; w.f = 0.f;
    if (i < 10){ float sc = g4[i] * rsqrtf(v4[i] + EPS_BN); w.f = b4[i] - m4[i] * sc; }
    ws[1232 + i] = w.u; }
}

// --- 4-pixel-per-thread dot macros. A = acc[out][4], H = h2[4] (one per pixel) ---
// accumulate 4 outputs x 4 pixels from one uint4 of packed weight pairs
#define DO4x(A, H, Q, O0) \
  { h2 w0_ = ash((Q).x), w1_ = ash((Q).y), w2_ = ash((Q).z), w3_ = ash((Q).w); \
    _Pragma("unroll") for (int j_ = 0; j_ < 4; j_++){ \
      A[(O0)+0][j_] = dot2(H[j_], w0_, A[(O0)+0][j_]); \
      A[(O0)+1][j_] = dot2(H[j_], w1_, A[(O0)+1][j_]); \
      A[(O0)+2][j_] = dot2(H[j_], w2_, A[(O0)+2][j_]); \
      A[(O0)+3][j_] = dot2(H[j_], w3_, A[(O0)+3][j_]); } }

// init variant: acc starts at bias (read from s[BB+O0..+3]) -- kills the v_mov init pass
#define DO4i(A, H, Q, O0, BB) \
  { h2 w0_ = ash((Q).x), w1_ = ash((Q).y), w2_ = ash((Q).z), w3_ = ash((Q).w); \
    float b0_ = asf(s[(BB)+(O0)+0]), b1_ = asf(s[(BB)+(O0)+1]); \
    float b2_ = asf(s[(BB)+(O0)+2]), b3_ = asf(s[(BB)+(O0)+3]); \
    _Pragma("unroll") for (int j_ = 0; j_ < 4; j_++){ \
      A[(O0)+0][j_] = dot2(H[j_], w0_, b0_); \
      A[(O0)+1][j_] = dot2(H[j_], w1_, b1_); \
      A[(O0)+2][j_] = dot2(H[j_], w2_, b2_); \
      A[(O0)+3][j_] = dot2(H[j_], w3_, b3_); } }

#define DO2x(A, H, Q2) \
  { h2 w0_ = ash((Q2).x), w1_ = ash((Q2).y); \
    _Pragma("unroll") for (int j_ = 0; j_ < 4; j_++){ \
      A[8][j_] = dot2(H[j_], w0_, A[8][j_]); \
      A[9][j_] = dot2(H[j_], w1_, A[9][j_]); } }

#define DO2i(A, H, Q2, BB) \
  { h2 w0_ = ash((Q2).x), w1_ = ash((Q2).y); \
    float b8_ = asf(s[(BB)+8]), b9_ = asf(s[(BB)+9]); \
    _Pragma("unroll") for (int j_ = 0; j_ < 4; j_++){ \
      A[8][j_] = dot2(H[j_], w0_, b8_); \
      A[9][j_] = dot2(H[j_], w1_, b9_); } }

// Fully fused per-pixel MLP, f32 in / f32 out, f16-dot2 internal math.
// Each thread handles 4 pixels (float4 per channel-plane load, 16B/lane coalescing).
extern "C" __global__ __launch_bounds__(256, 2) void fused_kernel(
  const float4* __restrict__ xf, const float4* __restrict__ xh1, const float4* __restrict__ xh2,
  const u32* __restrict__ wsp, float4* __restrict__ out)
{
  __shared__ __align__(16) u32 s[1248];
  for (int i = threadIdx.x; i < 1248; i += 256) s[i] = wsp[i];
  __syncthreads();

  const unsigned p  = blockIdx.x * 256u + threadIdx.x;  // pixel-quad index
  const unsigned b  = p >> 16;
  const unsigned hw = p & (HW4 - 1u);
  const size_t base = (size_t)b * (10u * HW4) + hw;
  const float4* A1 = xh1 + base;
  const float4* A2 = xh2 + base;
  const float4* AF = xf  + base;

  float a[32][4];     // conv1 accumulators [out][pixel]
  h2 ph[10][4];       // packed channel-pair inputs [cp][pixel]

  // ---- block 1 inputs: concat(xh1, xh2), 20 channels -> 10 pairs ----
  #pragma unroll
  for (int cp = 0; cp < 5; cp++){
    float4 c0 = A1[(size_t)(2*cp)     * HW4];
    float4 c1 = A1[(size_t)(2*cp + 1) * HW4];
    ph[cp][0] = pk(c0.x, c1.x); ph[cp][1] = pk(c0.y, c1.y);
    ph[cp][2] = pk(c0.z, c1.z); ph[cp][3] = pk(c0.w, c1.w);
  }
  #pragma unroll
  for (int cp = 0; cp < 5; cp++){
    float4 c0 = A2[(size_t)(2*cp)     * HW4];
    float4 c1 = A2[(size_t)(2*cp + 1) * HW4];
    ph[5+cp][0] = pk(c0.x, c1.x); ph[5+cp][1] = pk(c0.y, c1.y);
    ph[5+cp][2] = pk(c0.z, c1.z); ph[5+cp][3] = pk(c0.w, c1.w);
  }

  // ---- block 1, conv1: 20 -> 32 (cp=0 peeled to fold bias init) ----
  { const uint4* wr = (const uint4*)&s[0];
    #pragma unroll
    for (int jw = 0; jw < 8; jw++){ uint4 q = wr[jw]; DO4i(a, ph[0], q, 4*jw, 320); } }
  #pragma unroll
  for (int cp = 1; cp < 10; cp++){
    const uint4* wr = (const uint4*)&s[cp * 32];
    #pragma unroll
    for (int jw = 0; jw < 8; jw++){ uint4 q = wr[jw]; DO4x(a, ph[cp], q, 4*jw); }
  }
  #pragma unroll
  for (int o = 0; o < 32; o++){
    #pragma unroll
    for (int j = 0; j < 4; j++) a[o][j] = fmaxf(a[o][j], 0.f);
  }

  // ---- hoist xf loads: their HBM latency hides under block-1 conv2 ----
  #pragma unroll
  for (int cp = 0; cp < 5; cp++){
    float4 c0 = AF[(size_t)(2*cp)     * HW4];
    float4 c1 = AF[(size_t)(2*cp + 1) * HW4];
    ph[cp][0] = pk(c0.x, c1.x); ph[cp][1] = pk(c0.y, c1.y);
    ph[cp][2] = pk(c0.z, c1.z); ph[cp][3] = pk(c0.w, c1.w);
  }

  // ---- block 1, conv2: 32 -> 10 (message) ----
  h2 qh[16][4];
  #pragma unroll
  for (int k = 0; k < 16; k++){
    #pragma unroll
    for (int j = 0; j < 4; j++) qh[k][j] = pk(a[2*k][j], a[2*k+1][j]);
  }
  float m[10][4];
  { const uint4* wr = (const uint4*)&s[352];
    uint4 q0 = wr[0]; DO4i(m, qh[0], q0, 0, 608);
    uint4 q1 = wr[1]; DO4i(m, qh[0], q1, 4, 608);
    uint4 q2 = wr[2]; DO2i(m, qh[0], q2, 608); }
  #pragma unroll
  for (int cp = 1; cp < 16; cp++){
    const uint4* wr = (const uint4*)&s[352 + cp * 16];
    uint4 q0 = wr[0]; DO4x(m, qh[cp], q0, 0);
    uint4 q1 = wr[1]; DO4x(m, qh[cp], q1, 4);
    uint4 q2 = wr[2]; DO2x(m, qh[cp], q2);
  }
  #pragma unroll
  for (int o = 0; o < 10; o++){
    #pragma unroll
    for (int j = 0; j < 4; j++) m[o][j] = fmaxf(m[o][j], 0.f);
  }
  #pragma unroll
  for (int o = 0; o < 10; o++){
    float4 r; r.x = m[o][0]; r.y = m[o][1]; r.z = m[o][2]; r.w = m[o][3];
    out[MSG_OFF4 + base + (size_t)o * HW4] = r;
  }

  // ---- block 2, conv1: [xf;message](20) -> 32 ----
  #pragma unroll
  for (int k = 0; k < 5; k++){
    #pragma unroll
    for (int j = 0; j < 4; j++) ph[5+k][j] = pk(m[2*k][j], m[2*k+1][j]);
  }
  { const uint4* wr = (const uint4*)&s[624];
    #pragma unroll
    for (int jw = 0; jw < 8; jw++){ uint4 q = wr[jw]; DO4i(a, ph[0], q, 4*jw, 944); } }
  #pragma unroll
  for (int cp = 1; cp < 10; cp++){
    const uint4* wr = (const uint4*)&s[624 + cp * 32];
    #pragma unroll
    for (int jw = 0; jw < 8; jw++){ uint4 q = wr[jw]; DO4x(a, ph[cp], q, 4*jw); }
  }
  #pragma unroll
  for (int o = 0; o < 32; o++){
    #pragma unroll
    for (int j = 0; j < 4; j++) a[o][j] = fmaxf(a[o][j], 0.f);
  }

  // ---- block 2, conv2: 32 -> 10 (xf_new) ----
  #pragma unroll
  for (int k = 0; k < 16; k++){
    #pragma unroll
    for (int j = 0; j < 4; j++) qh[k][j] = pk(a[2*k][j], a[2*k+1][j]);
  }
  float oo[10][4];
  { const uint4* wr = (const uint4*)&s[976];
    uint4 q0 = wr[0]; DO4i(oo, qh[0], q0, 0, 1232);
    uint4 q1 = wr[1]; DO4i(oo, qh[0], q1, 4, 1232);
    uint4 q2 = wr[2]; DO2i(oo, qh[0], q2, 1232); }
  #pragma unroll
  for (int cp = 1; cp < 16; cp++){
    const uint4* wr = (const uint4*)&s[976 + cp * 16];
    uint4 q0 = wr[0]; DO4x(oo, qh[cp], q0, 0);
    uint4 q1 = wr[1]; DO4x(oo, qh[cp], q1, 4);
    uint4 q2 = wr[2]; DO2x(oo, qh[cp], q2);
  }
  #pragma unroll
  for (int o = 0; o < 10; o++){
    float4 r;
    r.x = fmaxf(oo[o][0], 0.f); r.y = fmaxf(oo[o][1], 0.f);
    r.z = fmaxf(oo[o][2], 0.f); r.w = fmaxf(oo[o][3], 0.f);
    out[base + (size_t)o * HW4] = r;
  }
}

extern "C" void kernel_launch(void* const* d_in, const int* in_sizes, int n_in,
                              void* d_out, int out_size, void* d_ws, size_t ws_size,
                              hipStream_t stream)
{
  u32* ws = (u32*)d_ws;
  prep_kernel<<<1, 256, 0, stream>>>(
    (const float*)d_in[3],  (const float*)d_in[4],  (const float*)d_in[5],  (const float*)d_in[6],  (const float*)d_in[7],
    (const float*)d_in[8],  (const float*)d_in[9],  (const float*)d_in[10], (const float*)d_in[11], (const float*)d_in[12],
    (const float*)d_in[13], (const float*)d_in[14], (const float*)d_in[15], (const float*)d_in[16], (const float*)d_in[17],
    (const float*)d_in[18], (const float*)d_in[19], (const float*)d_in[20], (const float*)d_in[21], (const float*)d_in[22],
    ws);

  // 8*512*512 pixels / 4 per thread = 524,288 threads = 2048 blocks x 256
  fused_kernel<<<2048, 256, 0, stream>>>(
    (const float4*)d_in[0], (const float4*)d_in[1], (const float4*)d_in[2],
    ws, (float4*)d_out);
}